// Round 3
// baseline (385.087 us; speedup 1.0000x reference)
//
#include <hip/hip_runtime.h>
#include <math.h>

#define NQ 12
#define DIM 4096
#define NGATES 36
#define NROUND 9

typedef float f32x2 __attribute__((ext_vector_type(2)));

// GF(2)-linear LDS swizzle (bijective on 12 bits): sw(a^b) = sw(a)^sw(b)
constexpr unsigned swz(unsigned x) { return x ^ (x >> 4); }

// ---- compile-time circuit plan: CNOTs folded into GF(2) index maps ----
// M: logical index i lives at physical index M(i). CNOT(bc<-ctrl, bt<-tgt):
// M <- M*C (col bc ^= col bt), M^-1 <- C*M^-1 (row bt ^= row bc).
// Gate on logical bit b: pair mask m = M*e_b, "1"-selector = row b of M^-1.
// 4 gates per round (same layer => parity(m_j & s_i) = delta_ij exactly).
struct Round {
  unsigned s[4];       // selectors of the 4 gates
  unsigned l[4];       // sorted pivot low-masks for 4-zero-bit insertion
  unsigned cbsw8[16];  // swizzled byte offsets of the 16 coset slots
};
struct PlanT {
  Round rd[NROUND];
  unsigned zsel[NQ];
};

constexpr PlanT make_plan() {
  PlanT P{};
  unsigned Mcol[NQ] = {}, Minv[NQ] = {};
  for (int i = 0; i < NQ; ++i) { Mcol[i] = 1u << i; Minv[i] = 1u << i; }
  unsigned gm[NGATES] = {}, gs[NGATES] = {};
  int g = 0;
  for (int L = 0; L < 3; ++L) {
    for (int q = 0; q < NQ; ++q) { int b = NQ - 1 - q; gm[g] = Mcol[b]; gs[g] = Minv[b]; ++g; }
    for (int q = 0; q < NQ; ++q) {
      int bc = NQ - 1 - q, bt = NQ - 1 - ((q + 1) % NQ);
      Mcol[bc] ^= Mcol[bt];
      Minv[bt] ^= Minv[bc];
    }
  }
  for (int r = 0; r < NROUND; ++r) {
    unsigned m[4], red[4];
    for (int k = 0; k < 4; ++k) { m[k] = gm[4*r+k]; red[k] = m[k]; P.rd[r].s[k] = gs[4*r+k]; }
    for (int a = 0; a < 4; ++a) {
      unsigned p = red[a] & (0u - red[a]);
      for (int b = a + 1; b < 4; ++b) if (red[b] & p) red[b] ^= red[a];
    }
    unsigned piv[4];
    for (int a = 0; a < 4; ++a) piv[a] = red[a] & (0u - red[a]);
    for (int a = 0; a < 4; ++a)
      for (int b = a + 1; b < 4; ++b)
        if (piv[a] > piv[b]) { unsigned tp = piv[a]; piv[a] = piv[b]; piv[b] = tp; }
    for (int a = 0; a < 4; ++a) P.rd[r].l[a] = piv[a] - 1u;
    for (int d = 0; d < 16; ++d) {
      unsigned c = 0;
      for (int k = 0; k < 4; ++k) if (d & (1 << k)) c ^= m[k];
      P.rd[r].cbsw8[d] = swz(c) << 3;
    }
  }
  for (int q = 0; q < NQ; ++q) P.zsel[q] = Minv[NQ - 1 - q];
  return P;
}

constexpr PlanT PLAN = make_plan();

// ---- prep: fuse U = RZ*RY*RX per (layer,qubit), emit 8 pre-negated packed
// coefficient pairs per gate -> d_ws[36*8 f32x2] ----
// (u0,u1),(-u1,u0),(u2,u3),(-u3,u2),(u4,u5),(-u5,u4),(u6,u7),(-u7,u6)
__global__ void qc_prep(const float* __restrict__ params, f32x2* __restrict__ gpk) {
  int t = threadIdx.x;
  if (t < NGATES) {
    float h1 = params[3*t+0]*0.5f, h2 = params[3*t+1]*0.5f, h3 = params[3*t+2]*0.5f;
    float c1 = cosf(h1), s1 = sinf(h1);
    float c2 = cosf(h2), s2 = sinf(h2);
    float c3 = cosf(h3), s3 = sinf(h3);
    float a00r =  c2*c1, a00i =  s2*s1;
    float a01r = -s2*c1, a01i = -c2*s1;
    float a10r =  s2*c1, a10i = -c2*s1;
    float a11r =  c2*c1, a11i = -s2*s1;
    float u[8];
    u[0] = c3*a00r + s3*a00i;  u[1] = c3*a00i - s3*a00r;
    u[2] = c3*a01r + s3*a01i;  u[3] = c3*a01i - s3*a01r;
    u[4] = c3*a10r - s3*a10i;  u[5] = c3*a10i + s3*a10r;
    u[6] = c3*a11r - s3*a11i;  u[7] = c3*a11i + s3*a11r;
    f32x2* o = gpk + t*8;
#pragma unroll
    for (int k = 0; k < 4; ++k) {
      f32x2 a, b;
      a[0] =  u[2*k];   a[1] = u[2*k+1];
      b[0] = -u[2*k+1]; b[1] = u[2*k];
      o[2*k]   = a;
      o[2*k+1] = b;
    }
  }
}

// ---- packed complex butterfly primitives (VOP3P, op_sel broadcasts) ----
// d.lo = c.lo*a.SEL + [d.lo]; d.hi = c.hi*a.SEL + [d.hi]; SEL in {lo,hi}.
// Pure-VALU asm: ordering enforced by register data deps, scheduler-safe.
#define PK_MUL_L(d, c, a) \
  asm("v_pk_mul_f32 %0, %1, %2 op_sel:[0,0] op_sel_hi:[1,0]" \
      : "=v"(d) : "v"(c), "v"(a))
#define PK_FMA_L(d, c, a) \
  asm("v_pk_fma_f32 %0, %1, %2, %0 op_sel:[0,0,0] op_sel_hi:[1,0,1]" \
      : "+v"(d) : "v"(c), "v"(a))
#define PK_FMA_H(d, c, a) \
  asm("v_pk_fma_f32 %0, %1, %2, %0 op_sel:[0,1,0] op_sel_hi:[1,1,1]" \
      : "+v"(d) : "v"(c), "v"(a))

__global__ __launch_bounds__(256)
__attribute__((amdgpu_waves_per_eu(5, 5)))
void qc_main(const float* __restrict__ x, const f32x2* __restrict__ gpk,
             float* __restrict__ out) {
  __shared__ float2 sst[DIM];        // exactly 32768 B -> 5 blocks/CU
  char* sb = (char*)sst;
  float* sf = (float*)sst;           // reduction scratch overlaid post-barrier
  const int t = threadIdx.x;
  const long row = blockIdx.x;

  // ---- stage x row (im=0), accumulate sum of squares ----
  const float4* x4 = (const float4*)(x + (size_t)row * DIM);
  float ssq = 0.f;
#pragma unroll
  for (int k = 0; k < 4; ++k) {
    float4 a = x4[t + 256*k];
    int j0 = 4*(t + 256*k);
    *(float2*)(sb + (swz((unsigned)j0)     << 3)) = make_float2(a.x, 0.f);
    *(float2*)(sb + (swz((unsigned)(j0+1)) << 3)) = make_float2(a.y, 0.f);
    *(float2*)(sb + (swz((unsigned)(j0+2)) << 3)) = make_float2(a.z, 0.f);
    *(float2*)(sb + (swz((unsigned)(j0+3)) << 3)) = make_float2(a.w, 0.f);
    ssq += a.x*a.x + a.y*a.y + a.z*a.z + a.w*a.w;
  }
#pragma unroll
  for (int off = 32; off > 0; off >>= 1) ssq += __shfl_down(ssq, off, 64);
  __syncthreads();

  // ---- 9 rounds of 4 generalized-bit gates; one LDS round-trip each ----
  // unroll 1: one round's live set fits the 102-VGPR budget (5 waves/EU).
#pragma unroll 1
  for (int r = 0; r < NROUND; ++r) {
    const unsigned s0 = PLAN.rd[r].s[0], sA = PLAN.rd[r].s[1];
    const unsigned sB = PLAN.rd[r].s[2], sC = PLAN.rd[r].s[3];
    const unsigned l0 = PLAN.rd[r].l[0], l1 = PLAN.rd[r].l[1];
    const unsigned l2 = PLAN.rd[r].l[2], l3 = PLAN.rd[r].l[3];
    unsigned cb[16];
#pragma unroll
    for (int d = 0; d < 16; ++d) cb[d] = PLAN.rd[r].cbsw8[d];

    unsigned j = (unsigned)t;
    j = ((j & ~l0) << 1) | (j & l0);
    j = ((j & ~l1) << 1) | (j & l1);
    j = ((j & ~l2) << 1) | (j & l2);
    j = ((j & ~l3) << 1) | (j & l3);
    // relabel (swizzled-byte domain; swizzle is GF(2)-linear)
    unsigned adj8 = 0;
    adj8 ^= (unsigned)(-(int)(__popc(j & s0) & 1)) & cb[1];
    adj8 ^= (unsigned)(-(int)(__popc(j & sA) & 1)) & cb[2];
    adj8 ^= (unsigned)(-(int)(__popc(j & sB) & 1)) & cb[4];
    adj8 ^= (unsigned)(-(int)(__popc(j & sC) & 1)) & cb[8];
    const unsigned base8 = ((j ^ (j >> 4)) << 3) ^ adj8;

    f32x2 v[16];
#pragma unroll
    for (int d = 0; d < 16; ++d)
      v[d] = *(const f32x2*)(sb + (base8 ^ cb[d]));

#pragma unroll
    for (int st = 0; st < 4; ++st) {
      // uniform-address coefficient loads (L1-resident; off the DS pipe)
      const f32x2* cp = gpk + (r * 4 + st) * 8;
      const f32x2 c0 = cp[0], c1 = cp[1], c2 = cp[2], c3 = cp[3];
      const f32x2 c4 = cp[4], c5 = cp[5], c6 = cp[6], c7 = cp[7];
#pragma unroll
      for (int d = 0; d < 16; ++d) {
        if (!(d & (1 << st))) {
          const int d1 = d | (1 << st);
          const f32x2 a0 = v[d], a1 = v[d1];
          f32x2 o0, o1;
          // o0 = U00*a0 + U01*a1 ; o1 = U10*a0 + U11*a1 (complex, packed)
          PK_MUL_L(o0, c0, a0);
          PK_FMA_H(o0, c1, a0);
          PK_FMA_L(o0, c2, a1);
          PK_FMA_H(o0, c3, a1);
          PK_MUL_L(o1, c4, a0);
          PK_FMA_H(o1, c5, a0);
          PK_FMA_L(o1, c6, a1);
          PK_FMA_H(o1, c7, a1);
          v[d] = o0; v[d1] = o1;
        }
      }
    }
#pragma unroll
    for (int d = 0; d < 16; ++d)
      *(f32x2*)(sb + (base8 ^ cb[d])) = v[d];
    __syncthreads();
  }

  // ---- measurement: 16 consecutive amps/thread, WHT over low 4 bits ----
  const unsigned mbase8 = (((16u * (unsigned)t) ^ (unsigned)t) << 3);
  float p[16];
#pragma unroll
  for (int c = 0; c < 16; ++c) {
    f32x2 v = *(const f32x2*)(sb + (mbase8 ^ ((unsigned)c << 3)));
    f32x2 sq = v * v;
    p[c] = sq[0] + sq[1];
  }
#pragma unroll
  for (int b = 0; b < 4; ++b) {
#pragma unroll
    for (int c = 0; c < 16; ++c) {
      if (!(c & (1 << b))) {
        const int c1 = c | (1 << b);
        float u = p[c], v = p[c1];
        p[c] = u + v; p[c1] = u - v;
      }
    }
  }
  float zs[NQ];
#pragma unroll
  for (int q = 0; q < NQ; ++q) {
    const unsigned m = PLAN.zsel[q];
    const float v = p[m & 15u];
    const int sgn = __popc((unsigned)t & (m >> 4)) & 1;
    zs[q] = sgn ? -v : v;
  }
#pragma unroll
  for (int q = 0; q < NQ; ++q) {
#pragma unroll
    for (int off = 32; off > 0; off >>= 1) zs[q] += __shfl_down(zs[q], off, 64);
  }
  __syncthreads();               // all state reads done; safe to overlay sf
  const int w = t >> 6;
  if ((t & 63) == 0) {
#pragma unroll
    for (int q = 0; q < NQ; ++q) sf[w*NQ + q] = zs[q];
    sf[48 + w] = ssq;
  }
  __syncthreads();
  if (t < NQ) {
    const float den = sf[48] + sf[49] + sf[50] + sf[51];
    const float tot = sf[t] + sf[NQ + t] + sf[2*NQ + t] + sf[3*NQ + t];
    out[row * NQ + t] = tot / den;
  }
}

extern "C" void kernel_launch(void* const* d_in, const int* in_sizes, int n_in,
                              void* d_out, int out_size, void* d_ws, size_t ws_size,
                              hipStream_t stream) {
  const float* x = (const float*)d_in[0];
  const float* params = (const float*)d_in[1];
  float* out = (float*)d_out;
  f32x2* gpk = (f32x2*)d_ws;                   // 36*8 packed coeff pairs
  const int nrows = in_sizes[0] / DIM;         // 8192
  qc_prep<<<dim3(1), dim3(64), 0, stream>>>(params, gpk);
  qc_main<<<dim3(nrows), dim3(256), 0, stream>>>(x, gpk, out);
}

// Round 4
// 375.624 us; speedup vs baseline: 1.0252x; 1.0252x over previous
//
#include <hip/hip_runtime.h>
#include <math.h>

#define NQ 12
#define DIM 4096
#define NGATES 36
#define NB 3                 // bits (gates) per round
#define NSLOT 8              // 2^NB amps per thread
#define NROUND 12            // 36 / NB
#define THREADS 512

typedef float f32x2 __attribute__((ext_vector_type(2)));

// GF(2)-linear LDS swizzle (bijective on 12 bits): sw(a^b) = sw(a)^sw(b)
constexpr unsigned swz(unsigned x) { return x ^ (x >> 4); }

// ---- compile-time circuit plan: CNOTs folded into GF(2) index maps ----
// M: logical index i lives at physical index M(i). CNOT(bc<-ctrl, bt<-tgt):
// M <- M*C (col bc ^= col bt), M^-1 <- C*M^-1 (row bt ^= row bc).
// Gate on logical bit b: pair mask m = M*e_b, "1"-selector = row b of M^-1.
// NB gates per round (same layer => parity(m_j & s_i) = delta_ij exactly).
struct Round {
  unsigned s[NB];          // selectors of the NB gates
  unsigned l[NB];          // sorted pivot low-masks for zero-bit insertion
  unsigned cbsw8[NSLOT];   // swizzled byte offsets of the coset slots
};
struct PlanT {
  Round rd[NROUND];
  unsigned zsel[NQ];
};

constexpr PlanT make_plan() {
  PlanT P{};
  unsigned Mcol[NQ] = {}, Minv[NQ] = {};
  for (int i = 0; i < NQ; ++i) { Mcol[i] = 1u << i; Minv[i] = 1u << i; }
  unsigned gm[NGATES] = {}, gs[NGATES] = {};
  int g = 0;
  for (int L = 0; L < 3; ++L) {
    for (int q = 0; q < NQ; ++q) { int b = NQ - 1 - q; gm[g] = Mcol[b]; gs[g] = Minv[b]; ++g; }
    for (int q = 0; q < NQ; ++q) {
      int bc = NQ - 1 - q, bt = NQ - 1 - ((q + 1) % NQ);
      Mcol[bc] ^= Mcol[bt];
      Minv[bt] ^= Minv[bc];
    }
  }
  for (int r = 0; r < NROUND; ++r) {
    unsigned m[NB], red[NB];
    for (int k = 0; k < NB; ++k) { m[k] = gm[NB*r+k]; red[k] = m[k]; P.rd[r].s[k] = gs[NB*r+k]; }
    for (int a = 0; a < NB; ++a) {
      unsigned p = red[a] & (0u - red[a]);
      for (int b = a + 1; b < NB; ++b) if (red[b] & p) red[b] ^= red[a];
    }
    unsigned piv[NB];
    for (int a = 0; a < NB; ++a) piv[a] = red[a] & (0u - red[a]);
    for (int a = 0; a < NB; ++a)
      for (int b = a + 1; b < NB; ++b)
        if (piv[a] > piv[b]) { unsigned tp = piv[a]; piv[a] = piv[b]; piv[b] = tp; }
    for (int a = 0; a < NB; ++a) P.rd[r].l[a] = piv[a] - 1u;
    for (int d = 0; d < NSLOT; ++d) {
      unsigned c = 0;
      for (int k = 0; k < NB; ++k) if (d & (1 << k)) c ^= m[k];
      P.rd[r].cbsw8[d] = swz(c) << 3;
    }
  }
  for (int q = 0; q < NQ; ++q) P.zsel[q] = Minv[NQ - 1 - q];
  return P;
}

constexpr PlanT PLAN = make_plan();

// ---- prep: fuse U = RZ*RY*RX per (layer,qubit), emit 8 pre-negated packed
// coefficient pairs per gate -> d_ws[36*8 f32x2] ----
// (u0,u1),(-u1,u0),(u2,u3),(-u3,u2),(u4,u5),(-u5,u4),(u6,u7),(-u7,u6)
__global__ void qc_prep(const float* __restrict__ params, f32x2* __restrict__ gpk) {
  int t = threadIdx.x;
  if (t < NGATES) {
    float h1 = params[3*t+0]*0.5f, h2 = params[3*t+1]*0.5f, h3 = params[3*t+2]*0.5f;
    float c1 = cosf(h1), s1 = sinf(h1);
    float c2 = cosf(h2), s2 = sinf(h2);
    float c3 = cosf(h3), s3 = sinf(h3);
    float a00r =  c2*c1, a00i =  s2*s1;
    float a01r = -s2*c1, a01i = -c2*s1;
    float a10r =  s2*c1, a10i = -c2*s1;
    float a11r =  c2*c1, a11i = -s2*s1;
    float u[8];
    u[0] = c3*a00r + s3*a00i;  u[1] = c3*a00i - s3*a00r;
    u[2] = c3*a01r + s3*a01i;  u[3] = c3*a01i - s3*a01r;
    u[4] = c3*a10r - s3*a10i;  u[5] = c3*a10i + s3*a10r;
    u[6] = c3*a11r - s3*a11i;  u[7] = c3*a11i + s3*a11r;
    f32x2* o = gpk + t*8;
#pragma unroll
    for (int k = 0; k < 4; ++k) {
      f32x2 a, b;
      a[0] =  u[2*k];   a[1] = u[2*k+1];
      b[0] = -u[2*k+1]; b[1] = u[2*k];
      o[2*k]   = a;
      o[2*k+1] = b;
    }
  }
}

__device__ __forceinline__ f32x2 blo(f32x2 a) { return __builtin_shufflevector(a, a, 0, 0); }
__device__ __forceinline__ f32x2 bhi(f32x2 a) { return __builtin_shufflevector(a, a, 1, 1); }

__global__ __launch_bounds__(THREADS)
__attribute__((amdgpu_waves_per_eu(8, 8)))
void qc_main(const float* __restrict__ x, const f32x2* __restrict__ gpk,
             float* __restrict__ out) {
  __shared__ float2 sst[DIM];        // exactly 32768 B -> 4-5 blocks/CU, 8 waves each
  char* sb = (char*)sst;
  float* sf = (float*)sst;           // reduction scratch overlaid post-barrier
  const int t = threadIdx.x;
  const long row = blockIdx.x;

  // ---- stage x row (im=0), accumulate sum of squares ----
  const float4* x4 = (const float4*)(x + (size_t)row * DIM);
  float ssq = 0.f;
#pragma unroll
  for (int k = 0; k < 2; ++k) {
    float4 a = x4[t + THREADS*k];
    int j0 = 4*(t + THREADS*k);
    *(float2*)(sb + (swz((unsigned)j0)     << 3)) = make_float2(a.x, 0.f);
    *(float2*)(sb + (swz((unsigned)(j0+1)) << 3)) = make_float2(a.y, 0.f);
    *(float2*)(sb + (swz((unsigned)(j0+2)) << 3)) = make_float2(a.z, 0.f);
    *(float2*)(sb + (swz((unsigned)(j0+3)) << 3)) = make_float2(a.w, 0.f);
    ssq += a.x*a.x + a.y*a.y + a.z*a.z + a.w*a.w;
  }
#pragma unroll
  for (int off = 32; off > 0; off >>= 1) ssq += __shfl_down(ssq, off, 64);
  __syncthreads();

  // ---- 12 rounds of 3 generalized-bit gates; one LDS round-trip each ----
#pragma unroll 1
  for (int r = 0; r < NROUND; ++r) {
    const unsigned s0 = PLAN.rd[r].s[0], sA = PLAN.rd[r].s[1], sB = PLAN.rd[r].s[2];
    const unsigned l0 = PLAN.rd[r].l[0], l1 = PLAN.rd[r].l[1], l2 = PLAN.rd[r].l[2];
    unsigned cb[NSLOT];
#pragma unroll
    for (int d = 0; d < NSLOT; ++d) cb[d] = PLAN.rd[r].cbsw8[d];

    // expand 9 thread bits to 12-bit coset representative (zeros at pivots)
    unsigned j = (unsigned)t;
    j = ((j & ~l0) << 1) | (j & l0);
    j = ((j & ~l1) << 1) | (j & l1);
    j = ((j & ~l2) << 1) | (j & l2);
    // relabel (swizzled-byte domain; swizzle is GF(2)-linear)
    unsigned adj8 = 0;
    adj8 ^= (unsigned)(-(int)(__popc(j & s0) & 1)) & cb[1];
    adj8 ^= (unsigned)(-(int)(__popc(j & sA) & 1)) & cb[2];
    adj8 ^= (unsigned)(-(int)(__popc(j & sB) & 1)) & cb[4];
    const unsigned base8 = ((j ^ (j >> 4)) << 3) ^ adj8;

    f32x2 v[NSLOT];
#pragma unroll
    for (int d = 0; d < NSLOT; ++d)
      v[d] = *(const f32x2*)(sb + (base8 ^ cb[d]));

#pragma unroll
    for (int st = 0; st < NB; ++st) {
      // uniform-address coefficient loads (L1-resident; off the DS pipe)
      const f32x2* cp = gpk + (r * NB + st) * 8;
      const f32x2 c0 = cp[0], c1 = cp[1], c2 = cp[2], c3 = cp[3];
      const f32x2 c4 = cp[4], c5 = cp[5], c6 = cp[6], c7 = cp[7];
#pragma unroll
      for (int d = 0; d < NSLOT; ++d) {
        if (!(d & (1 << st))) {
          const int d1 = d | (1 << st);
          const f32x2 a0 = v[d], a1 = v[d1];
          f32x2 o0 = c0 * blo(a0);
          o0 += c1 * bhi(a0);
          o0 += c2 * blo(a1);
          o0 += c3 * bhi(a1);
          f32x2 o1 = c4 * blo(a0);
          o1 += c5 * bhi(a0);
          o1 += c6 * blo(a1);
          o1 += c7 * bhi(a1);
          v[d] = o0; v[d1] = o1;
        }
      }
    }
#pragma unroll
    for (int d = 0; d < NSLOT; ++d)
      *(f32x2*)(sb + (base8 ^ cb[d])) = v[d];
    __syncthreads();
  }

  // ---- measurement: 8 consecutive amps/thread, WHT over low 3 bits ----
  // amps [8t, 8t+8): swz(8t+c) = (8t ^ c) ^ (t>>1)  (no carries, c<8)
  const unsigned mbase8 = (((8u * (unsigned)t) ^ ((unsigned)t >> 1)) << 3);
  float p[NSLOT];
#pragma unroll
  for (int c = 0; c < NSLOT; ++c) {
    f32x2 v = *(const f32x2*)(sb + (mbase8 ^ ((unsigned)c << 3)));
    f32x2 sq = v * v;
    p[c] = sq[0] + sq[1];
  }
#pragma unroll
  for (int b = 0; b < NB; ++b) {
#pragma unroll
    for (int c = 0; c < NSLOT; ++c) {
      if (!(c & (1 << b))) {
        const int c1 = c | (1 << b);
        float u = p[c], v = p[c1];
        p[c] = u + v; p[c1] = u - v;
      }
    }
  }
  float zs[NQ];
#pragma unroll
  for (int q = 0; q < NQ; ++q) {
    const unsigned m = PLAN.zsel[q];
    const float v = p[m & 7u];
    const int sgn = __popc((unsigned)t & (m >> 3)) & 1;
    zs[q] = sgn ? -v : v;
  }
#pragma unroll
  for (int q = 0; q < NQ; ++q) {
#pragma unroll
    for (int off = 32; off > 0; off >>= 1) zs[q] += __shfl_down(zs[q], off, 64);
  }
  __syncthreads();               // all state reads done; safe to overlay sf
  const int w = t >> 6;          // 8 waves
  if ((t & 63) == 0) {
#pragma unroll
    for (int q = 0; q < NQ; ++q) sf[w*NQ + q] = zs[q];
    sf[96 + w] = ssq;
  }
  __syncthreads();
  if (t < NQ) {
    float den = 0.f, tot = 0.f;
#pragma unroll
    for (int k = 0; k < 8; ++k) { den += sf[96 + k]; tot += sf[k*NQ + t]; }
    out[row * NQ + t] = tot / den;
  }
}

extern "C" void kernel_launch(void* const* d_in, const int* in_sizes, int n_in,
                              void* d_out, int out_size, void* d_ws, size_t ws_size,
                              hipStream_t stream) {
  const float* x = (const float*)d_in[0];
  const float* params = (const float*)d_in[1];
  float* out = (float*)d_out;
  f32x2* gpk = (f32x2*)d_ws;                   // 36*8 packed coeff pairs
  const int nrows = in_sizes[0] / DIM;         // 8192
  qc_prep<<<dim3(1), dim3(64), 0, stream>>>(params, gpk);
  qc_main<<<dim3(nrows), dim3(THREADS), 0, stream>>>(x, gpk, out);
}

// Round 6
// 327.162 us; speedup vs baseline: 1.1771x; 1.1481x over previous
//
#include <hip/hip_runtime.h>
#include <math.h>

#define NQ 12
#define DIM 4096
#define NGATES 36
#define NROUND 9

typedef float f32x4 __attribute__((ext_vector_type(4)));
typedef __fp16 fp16x2 __attribute__((ext_vector_type(2)));
typedef __fp16 fp16x4 __attribute__((ext_vector_type(4)));
typedef __fp16 fp16x8 __attribute__((ext_vector_type(8)));

// GF(2)-linear LDS swizzle (bijective on 12 bits): sw(a^b) = sw(a)^sw(b)
constexpr unsigned swz(unsigned x) { return x ^ (x >> 4); }

// ---- compile-time circuit plan: CNOTs folded into GF(2) index maps ----
// Gate on logical bit b: pair mask m = M*e_b, "1"-selector = row b of M^-1.
// 4 gates per round; round = dense 16x16 complex matrix on the 4-bit slot
// subspace, applied to 256 cosets via MFMA (K=32 re/im-interleaved).
struct Round {
  unsigned s[4];       // selectors of the 4 gates
  unsigned l[4];       // sorted pivot low-masks for 4-zero-bit insertion
  unsigned cbsw8[16];  // swizzled byte offsets of the 16 coset slots
  unsigned dt[4];      // base8 XOR-delta for coset c ^= tt*16 (tile step)
};
struct PlanT {
  Round rd[NROUND];
  unsigned zsel[NQ];
};

constexpr PlanT make_plan() {
  PlanT P{};
  unsigned Mcol[NQ] = {}, Minv[NQ] = {};
  for (int i = 0; i < NQ; ++i) { Mcol[i] = 1u << i; Minv[i] = 1u << i; }
  unsigned gm[NGATES] = {}, gs[NGATES] = {};
  int g = 0;
  for (int L = 0; L < 3; ++L) {
    for (int q = 0; q < NQ; ++q) { int b = NQ - 1 - q; gm[g] = Mcol[b]; gs[g] = Minv[b]; ++g; }
    for (int q = 0; q < NQ; ++q) {
      int bc = NQ - 1 - q, bt = NQ - 1 - ((q + 1) % NQ);
      Mcol[bc] ^= Mcol[bt];
      Minv[bt] ^= Minv[bc];
    }
  }
  for (int r = 0; r < NROUND; ++r) {
    unsigned m[4], red[4];
    for (int k = 0; k < 4; ++k) { m[k] = gm[4*r+k]; red[k] = m[k]; P.rd[r].s[k] = gs[4*r+k]; }
    for (int a = 0; a < 4; ++a) {
      unsigned p = red[a] & (0u - red[a]);
      for (int b = a + 1; b < 4; ++b) if (red[b] & p) red[b] ^= red[a];
    }
    unsigned piv[4];
    for (int a = 0; a < 4; ++a) piv[a] = red[a] & (0u - red[a]);
    for (int a = 0; a < 4; ++a)
      for (int b = a + 1; b < 4; ++b)
        if (piv[a] > piv[b]) { unsigned tp = piv[a]; piv[a] = piv[b]; piv[b] = tp; }
    for (int a = 0; a < 4; ++a) P.rd[r].l[a] = piv[a] - 1u;
    for (int d = 0; d < 16; ++d) {
      unsigned c = 0;
      for (int k = 0; k < 4; ++k) if (d & (1 << k)) c ^= m[k];
      P.rd[r].cbsw8[d] = swz(c) << 3;
    }
    // tile deltas: full base8-linear image of coset step tt*16
    for (int tt = 0; tt < 4; ++tt) {
      unsigned c = (unsigned)tt << 4;
      unsigned j = c;
      j = ((j & ~P.rd[r].l[0]) << 1) | (j & P.rd[r].l[0]);
      j = ((j & ~P.rd[r].l[1]) << 1) | (j & P.rd[r].l[1]);
      j = ((j & ~P.rd[r].l[2]) << 1) | (j & P.rd[r].l[2]);
      j = ((j & ~P.rd[r].l[3]) << 1) | (j & P.rd[r].l[3]);
      unsigned d = swz(j) << 3;
      for (int k = 0; k < 4; ++k)
        if (__builtin_popcount(j & P.rd[r].s[k]) & 1) d ^= P.rd[r].cbsw8[1u << k];
      P.rd[r].dt[tt] = d;
    }
  }
  for (int q = 0; q < NQ; ++q) P.zsel[q] = Minv[NQ - 1 - q];
  return P;
}

constexpr PlanT PLAN = make_plan();

// ---- prep: per round build the dense 16x16 complex tensor-product matrix,
// emit 4 fp16 A-operand matrices [16 rows s][32 k] row-major:
//   Are: [s][2j]=Re U[s][j], [s][2j+1]=-Im U[s][j]   (hi and lo split)
//   Aim: [s][2j]=Im U[s][j], [s][2j+1]= Re U[s][j]
// layout: amat + r*2048 + matid*512 + s*32 + k  (halves); matid 0..3 =
// Are_hi, Are_lo, Aim_hi, Aim_lo. 16B-aligned fragments.
__global__ void qc_prep(const float* __restrict__ params, __fp16* __restrict__ amat) {
  int t = threadIdx.x;             // 256 threads; 144 used
  int r = t >> 4, s = t & 15;
  if (r >= NROUND) return;
  float U[4][8];
  for (int k = 0; k < 4; ++k) {
    int gg = r * 4 + k;
    float h1 = params[3*gg+0]*0.5f, hh2 = params[3*gg+1]*0.5f, h3 = params[3*gg+2]*0.5f;
    float c1 = cosf(h1), s1 = sinf(h1);
    float c2 = cosf(hh2), s2 = sinf(hh2);
    float c3 = cosf(h3), s3 = sinf(h3);
    float a00r =  c2*c1, a00i =  s2*s1;
    float a01r = -s2*c1, a01i = -c2*s1;
    float a10r =  s2*c1, a10i = -c2*s1;
    float a11r =  c2*c1, a11i = -s2*s1;
    U[k][0] = c3*a00r + s3*a00i;  U[k][1] = c3*a00i - s3*a00r;
    U[k][2] = c3*a01r + s3*a01i;  U[k][3] = c3*a01i - s3*a01r;
    U[k][4] = c3*a10r - s3*a10i;  U[k][5] = c3*a10i + s3*a10r;
    U[k][6] = c3*a11r - s3*a11i;  U[k][7] = c3*a11i + s3*a11r;
  }
  __fp16* b0 = amat + r*2048 + s*32;   // Are_hi row
  __fp16* b1 = b0 + 512;               // Are_lo
  __fp16* b2 = b0 + 1024;              // Aim_hi
  __fp16* b3 = b0 + 1536;              // Aim_lo
  for (int j = 0; j < 16; ++j) {
    float pr = 1.f, pi = 0.f;
    for (int k = 0; k < 4; ++k) {
      int idx = ((((s >> k) & 1) * 2) + ((j >> k) & 1)) * 2;
      float gr = U[k][idx], gi = U[k][idx + 1];
      float npr = pr * gr - pi * gi;
      pi = pr * gi + pi * gr;
      pr = npr;
    }
    float v0_ =  pr; __fp16 e0 = (__fp16)v0_;
    float v1_ = -pi; __fp16 e1 = (__fp16)v1_;
    float v2_ =  pi; __fp16 e2 = (__fp16)v2_;
    float v3_ =  pr; __fp16 e3 = (__fp16)v3_;
    b0[2*j]   = e0;  b1[2*j]   = (__fp16)(v0_ - (float)e0);
    b0[2*j+1] = e1;  b1[2*j+1] = (__fp16)(v1_ - (float)e1);
    b2[2*j]   = e2;  b3[2*j]   = (__fp16)(v2_ - (float)e2);
    b2[2*j+1] = e3;  b3[2*j+1] = (__fp16)(v3_ - (float)e3);
  }
}

__global__ __launch_bounds__(256)
__attribute__((amdgpu_waves_per_eu(4, 5)))
void qc_main(const float* __restrict__ x, const __fp16* __restrict__ amat,
             float* __restrict__ out) {
  __shared__ float2 sst[DIM];        // 32768 B
  char* sb = (char*)sst;
  float* sf = (float*)sst;           // reduction scratch overlaid post-barrier
  const int t = threadIdx.x;
  const long row = blockIdx.x;

  // ---- stage x row (im=0), accumulate sum of squares ----
  const float4* x4 = (const float4*)(x + (size_t)row * DIM);
  float ssq = 0.f;
#pragma unroll
  for (int k = 0; k < 4; ++k) {
    float4 a = x4[t + 256*k];
    int j0 = 4*(t + 256*k);
    *(float2*)(sb + (swz((unsigned)j0)     << 3)) = make_float2(a.x, 0.f);
    *(float2*)(sb + (swz((unsigned)(j0+1)) << 3)) = make_float2(a.y, 0.f);
    *(float2*)(sb + (swz((unsigned)(j0+2)) << 3)) = make_float2(a.z, 0.f);
    *(float2*)(sb + (swz((unsigned)(j0+3)) << 3)) = make_float2(a.w, 0.f);
    ssq += a.x*a.x + a.y*a.y + a.z*a.z + a.w*a.w;
  }
#pragma unroll
  for (int off = 32; off > 0; off >>= 1) ssq += __shfl_down(ssq, off, 64);
  __syncthreads();

  // ---- 9 rounds; each round = dense 16x16 complex gate-product via MFMA.
  // Wave w handles tiles 4w+tt (16 cosets each). Lane l: coset col = l&15,
  // slots 4q..4q+3 with q = l>>4 (A/B K-fragment AND C/D row mapping agree,
  // so per-lane read-set == write-set; no intra-round barrier needed).
#pragma unroll 1
  for (int r = 0; r < NROUND; ++r) {
    const unsigned s0 = PLAN.rd[r].s[0], sA = PLAN.rd[r].s[1];
    const unsigned sB = PLAN.rd[r].s[2], sC = PLAN.rd[r].s[3];
    const unsigned l0 = PLAN.rd[r].l[0], l1 = PLAN.rd[r].l[1];
    const unsigned l2 = PLAN.rd[r].l[2], l3 = PLAN.rd[r].l[3];
    const unsigned CB1 = PLAN.rd[r].cbsw8[1], CB2 = PLAN.rd[r].cbsw8[2];
    const unsigned CB3 = PLAN.rd[r].cbsw8[3];
    const unsigned C4 = PLAN.rd[r].cbsw8[4], C8 = PLAN.rd[r].cbsw8[8];
    const unsigned D1 = PLAN.rd[r].dt[1], D2 = PLAN.rd[r].dt[2];
    const unsigned D3 = PLAN.rd[r].dt[3];

    // coset for tile 0: c0 = wave*64 + (lane&15)
    unsigned j = ((unsigned)t & 0xC0u) | ((unsigned)t & 15u);
    j = ((j & ~l0) << 1) | (j & l0);
    j = ((j & ~l1) << 1) | (j & l1);
    j = ((j & ~l2) << 1) | (j & l2);
    j = ((j & ~l3) << 1) | (j & l3);
    unsigned adj8 = 0;
    adj8 ^= (unsigned)(-(int)(__popc(j & s0) & 1)) & CB1;
    adj8 ^= (unsigned)(-(int)(__popc(j & sA) & 1)) & CB2;
    adj8 ^= (unsigned)(-(int)(__popc(j & sB) & 1)) & C4;
    adj8 ^= (unsigned)(-(int)(__popc(j & sC) & 1)) & C8;
    const unsigned q = ((unsigned)t >> 4) & 3u;
    const unsigned qsel = ((q & 1u) ? C4 : 0u) ^ ((q & 2u) ? C8 : 0u);
    const unsigned b0a = (((j ^ (j >> 4)) << 3) ^ adj8) ^ qsel;

    // A-operand fragments (uniform-ish global loads; L1/L2 resident)
    const fp16x8* am = (const fp16x8*)(amat + (size_t)r * 2048);
    const int fo = (t & 15) * 4 + (int)q;
    const fp16x8 Arh = am[fo];
    const fp16x8 Arl = am[64 + fo];
    const fp16x8 Aih = am[128 + fo];
    const fp16x8 Ail = am[192 + fo];

#pragma unroll
    for (int tt = 0; tt < 4; ++tt) {
      const unsigned bb = b0a ^ (tt == 0 ? 0u : tt == 1 ? D1 : tt == 2 ? D2 : D3);
      const unsigned a0 = bb, a1 = bb ^ CB1, a2 = bb ^ CB2, a3 = bb ^ CB3;
      const float2 A0 = *(const float2*)(sb + a0);
      const float2 A1 = *(const float2*)(sb + a1);
      const float2 A2 = *(const float2*)(sb + a2);
      const float2 A3 = *(const float2*)(sb + a3);
      // B fragment: k = q*8 + 2*jj + comp -> amp slot 4q+jj, re/im interleave
      fp16x2 p0 = __builtin_amdgcn_cvt_pkrtz(A0.x, A0.y);
      fp16x2 p1 = __builtin_amdgcn_cvt_pkrtz(A1.x, A1.y);
      fp16x2 p2 = __builtin_amdgcn_cvt_pkrtz(A2.x, A2.y);
      fp16x2 p3 = __builtin_amdgcn_cvt_pkrtz(A3.x, A3.y);
      fp16x2 q0 = __builtin_amdgcn_cvt_pkrtz(A0.x - (float)p0[0], A0.y - (float)p0[1]);
      fp16x2 q1 = __builtin_amdgcn_cvt_pkrtz(A1.x - (float)p1[0], A1.y - (float)p1[1]);
      fp16x2 q2 = __builtin_amdgcn_cvt_pkrtz(A2.x - (float)p2[0], A2.y - (float)p2[1]);
      fp16x2 q3 = __builtin_amdgcn_cvt_pkrtz(A3.x - (float)p3[0], A3.y - (float)p3[1]);
      fp16x4 u01 = __builtin_shufflevector(p0, p1, 0, 1, 2, 3);
      fp16x4 u23 = __builtin_shufflevector(p2, p3, 0, 1, 2, 3);
      fp16x8 Bhi = __builtin_shufflevector(u01, u23, 0, 1, 2, 3, 4, 5, 6, 7);
      fp16x4 w01 = __builtin_shufflevector(q0, q1, 0, 1, 2, 3);
      fp16x4 w23 = __builtin_shufflevector(q2, q3, 0, 1, 2, 3);
      fp16x8 Blo = __builtin_shufflevector(w01, w23, 0, 1, 2, 3, 4, 5, 6, 7);

      f32x4 are = {0.f, 0.f, 0.f, 0.f}, aim = {0.f, 0.f, 0.f, 0.f};
      are = __builtin_amdgcn_mfma_f32_16x16x32_f16(Arh, Bhi, are, 0, 0, 0);
      are = __builtin_amdgcn_mfma_f32_16x16x32_f16(Arl, Bhi, are, 0, 0, 0);
      are = __builtin_amdgcn_mfma_f32_16x16x32_f16(Arh, Blo, are, 0, 0, 0);
      are = __builtin_amdgcn_mfma_f32_16x16x32_f16(Arl, Blo, are, 0, 0, 0);
      aim = __builtin_amdgcn_mfma_f32_16x16x32_f16(Aih, Bhi, aim, 0, 0, 0);
      aim = __builtin_amdgcn_mfma_f32_16x16x32_f16(Ail, Bhi, aim, 0, 0, 0);
      aim = __builtin_amdgcn_mfma_f32_16x16x32_f16(Aih, Blo, aim, 0, 0, 0);
      aim = __builtin_amdgcn_mfma_f32_16x16x32_f16(Ail, Blo, aim, 0, 0, 0);

      // C/D layout: col = lane&15 (coset), row = q*4+reg (slot) -> same addrs
      *(float2*)(sb + a0) = make_float2(are[0], aim[0]);
      *(float2*)(sb + a1) = make_float2(are[1], aim[1]);
      *(float2*)(sb + a2) = make_float2(are[2], aim[2]);
      *(float2*)(sb + a3) = make_float2(are[3], aim[3]);
    }
    __syncthreads();
  }

  // ---- measurement: 16 consecutive amps/thread, WHT over low 4 bits ----
  const unsigned mbase8 = (((16u * (unsigned)t) ^ (unsigned)t) << 3);
  float p[16];
#pragma unroll
  for (int c = 0; c < 16; ++c) {
    float2 v = *(const float2*)(sb + (mbase8 ^ ((unsigned)c << 3)));
    p[c] = v.x * v.x + v.y * v.y;
  }
#pragma unroll
  for (int b = 0; b < 4; ++b) {
#pragma unroll
    for (int c = 0; c < 16; ++c) {
      if (!(c & (1 << b))) {
        const int c1 = c | (1 << b);
        float u = p[c], v = p[c1];
        p[c] = u + v; p[c1] = u - v;
      }
    }
  }
  float zs[NQ];
#pragma unroll
  for (int qq = 0; qq < NQ; ++qq) {
    const unsigned m = PLAN.zsel[qq];
    const float v = p[m & 15u];
    const int sgn = __popc((unsigned)t & (m >> 4)) & 1;
    zs[qq] = sgn ? -v : v;
  }
#pragma unroll
  for (int qq = 0; qq < NQ; ++qq) {
#pragma unroll
    for (int off = 32; off > 0; off >>= 1) zs[qq] += __shfl_down(zs[qq], off, 64);
  }
  __syncthreads();               // all state reads done; safe to overlay sf
  const int w = t >> 6;
  if ((t & 63) == 0) {
#pragma unroll
    for (int qq = 0; qq < NQ; ++qq) sf[w*NQ + qq] = zs[qq];
    sf[48 + w] = ssq;
  }
  __syncthreads();
  if (t < NQ) {
    const float den = sf[48] + sf[49] + sf[50] + sf[51];
    const float tot = sf[t] + sf[NQ + t] + sf[2*NQ + t] + sf[3*NQ + t];
    out[row * NQ + t] = tot / den;
  }
}

extern "C" void kernel_launch(void* const* d_in, const int* in_sizes, int n_in,
                              void* d_out, int out_size, void* d_ws, size_t ws_size,
                              hipStream_t stream) {
  const float* x = (const float*)d_in[0];
  const float* params = (const float*)d_in[1];
  float* out = (float*)d_out;
  __fp16* amat = (__fp16*)d_ws;                // 9 rounds * 4 mats * 16x32 fp16
  const int nrows = in_sizes[0] / DIM;         // 8192
  qc_prep<<<dim3(1), dim3(256), 0, stream>>>(params, amat);
  qc_main<<<dim3(nrows), dim3(256), 0, stream>>>(x, amat, out);
}

// Round 7
// 302.291 us; speedup vs baseline: 1.2739x; 1.0823x over previous
//
#include <hip/hip_runtime.h>
#include <math.h>

#define NQ 12
#define DIM 4096
#define NGATES 36
#define NROUND 9

typedef float f32x4 __attribute__((ext_vector_type(4)));
typedef __fp16 fp16x2 __attribute__((ext_vector_type(2)));
typedef __fp16 fp16x4 __attribute__((ext_vector_type(4)));
typedef __fp16 fp16x8 __attribute__((ext_vector_type(8)));

// GF(2)-linear LDS swizzle (bijective on 12 bits): sw(a^b) = sw(a)^sw(b)
constexpr unsigned swz(unsigned x) { return x ^ (x >> 4); }

// ---- compile-time circuit plan: CNOTs folded into GF(2) index maps ----
// Gate on logical bit b: pair mask m = M*e_b, "1"-selector = row b of M^-1.
// 4 gates per round; round = dense 16x16 complex matrix on the 4-bit slot
// subspace, applied to 256 cosets via MFMA (K=32 re/im-interleaved).
struct Round {
  unsigned s[4];       // selectors of the 4 gates
  unsigned l[4];       // sorted pivot low-masks for 4-zero-bit insertion
  unsigned cbsw8[16];  // swizzled byte offsets of the 16 coset slots
  unsigned dt[4];      // base8 XOR-delta for coset c ^= tt*16 (tile step)
};
struct PlanT {
  Round rd[NROUND];
  unsigned zsel[NQ];
};

constexpr PlanT make_plan() {
  PlanT P{};
  unsigned Mcol[NQ] = {}, Minv[NQ] = {};
  for (int i = 0; i < NQ; ++i) { Mcol[i] = 1u << i; Minv[i] = 1u << i; }
  unsigned gm[NGATES] = {}, gs[NGATES] = {};
  int g = 0;
  for (int L = 0; L < 3; ++L) {
    for (int q = 0; q < NQ; ++q) { int b = NQ - 1 - q; gm[g] = Mcol[b]; gs[g] = Minv[b]; ++g; }
    for (int q = 0; q < NQ; ++q) {
      int bc = NQ - 1 - q, bt = NQ - 1 - ((q + 1) % NQ);
      Mcol[bc] ^= Mcol[bt];
      Minv[bt] ^= Minv[bc];
    }
  }
  for (int r = 0; r < NROUND; ++r) {
    unsigned m[4], red[4];
    for (int k = 0; k < 4; ++k) { m[k] = gm[4*r+k]; red[k] = m[k]; P.rd[r].s[k] = gs[4*r+k]; }
    for (int a = 0; a < 4; ++a) {
      unsigned p = red[a] & (0u - red[a]);
      for (int b = a + 1; b < 4; ++b) if (red[b] & p) red[b] ^= red[a];
    }
    unsigned piv[4];
    for (int a = 0; a < 4; ++a) piv[a] = red[a] & (0u - red[a]);
    for (int a = 0; a < 4; ++a)
      for (int b = a + 1; b < 4; ++b)
        if (piv[a] > piv[b]) { unsigned tp = piv[a]; piv[a] = piv[b]; piv[b] = tp; }
    for (int a = 0; a < 4; ++a) P.rd[r].l[a] = piv[a] - 1u;
    for (int d = 0; d < 16; ++d) {
      unsigned c = 0;
      for (int k = 0; k < 4; ++k) if (d & (1 << k)) c ^= m[k];
      P.rd[r].cbsw8[d] = swz(c) << 3;
    }
    // tile deltas: full base8-linear image of coset step tt*16
    for (int tt = 0; tt < 4; ++tt) {
      unsigned c = (unsigned)tt << 4;
      unsigned j = c;
      j = ((j & ~P.rd[r].l[0]) << 1) | (j & P.rd[r].l[0]);
      j = ((j & ~P.rd[r].l[1]) << 1) | (j & P.rd[r].l[1]);
      j = ((j & ~P.rd[r].l[2]) << 1) | (j & P.rd[r].l[2]);
      j = ((j & ~P.rd[r].l[3]) << 1) | (j & P.rd[r].l[3]);
      unsigned d = swz(j) << 3;
      for (int k = 0; k < 4; ++k)
        if (__builtin_popcount(j & P.rd[r].s[k]) & 1) d ^= P.rd[r].cbsw8[1u << k];
      P.rd[r].dt[tt] = d;
    }
  }
  for (int q = 0; q < NQ; ++q) P.zsel[q] = Minv[NQ - 1 - q];
  return P;
}

constexpr PlanT PLAN = make_plan();

// ---- prep: per round build the dense 16x16 complex tensor-product matrix,
// emit 4 fp16 A-operand matrices [16 rows s][32 k] row-major:
//   Are: [s][2j]=Re U[s][j], [s][2j+1]=-Im U[s][j]   (hi and lo split)
//   Aim: [s][2j]=Im U[s][j], [s][2j+1]= Re U[s][j]
// layout: amat + r*2048 + matid*512 + s*32 + k  (halves); matid 0..3 =
// Are_hi, Are_lo, Aim_hi, Aim_lo. 16B-aligned fragments.
__global__ void qc_prep(const float* __restrict__ params, __fp16* __restrict__ amat) {
  int t = threadIdx.x;             // 256 threads; 144 used
  int r = t >> 4, s = t & 15;
  if (r >= NROUND) return;
  float U[4][8];
  for (int k = 0; k < 4; ++k) {
    int gg = r * 4 + k;
    float h1 = params[3*gg+0]*0.5f, hh2 = params[3*gg+1]*0.5f, h3 = params[3*gg+2]*0.5f;
    float c1 = cosf(h1), s1 = sinf(h1);
    float c2 = cosf(hh2), s2 = sinf(hh2);
    float c3 = cosf(h3), s3 = sinf(h3);
    float a00r =  c2*c1, a00i =  s2*s1;
    float a01r = -s2*c1, a01i = -c2*s1;
    float a10r =  s2*c1, a10i = -c2*s1;
    float a11r =  c2*c1, a11i = -s2*s1;
    U[k][0] = c3*a00r + s3*a00i;  U[k][1] = c3*a00i - s3*a00r;
    U[k][2] = c3*a01r + s3*a01i;  U[k][3] = c3*a01i - s3*a01r;
    U[k][4] = c3*a10r - s3*a10i;  U[k][5] = c3*a10i + s3*a10r;
    U[k][6] = c3*a11r - s3*a11i;  U[k][7] = c3*a11i + s3*a11r;
  }
  __fp16* b0 = amat + r*2048 + s*32;   // Are_hi row
  __fp16* b1 = b0 + 512;               // Are_lo
  __fp16* b2 = b0 + 1024;              // Aim_hi
  __fp16* b3 = b0 + 1536;              // Aim_lo
  for (int j = 0; j < 16; ++j) {
    float pr = 1.f, pi = 0.f;
    for (int k = 0; k < 4; ++k) {
      int idx = ((((s >> k) & 1) * 2) + ((j >> k) & 1)) * 2;
      float gr = U[k][idx], gi = U[k][idx + 1];
      float npr = pr * gr - pi * gi;
      pi = pr * gi + pi * gr;
      pr = npr;
    }
    float v0_ =  pr; __fp16 e0 = (__fp16)v0_;
    float v1_ = -pi; __fp16 e1 = (__fp16)v1_;
    float v2_ =  pi; __fp16 e2 = (__fp16)v2_;
    float v3_ =  pr; __fp16 e3 = (__fp16)v3_;
    b0[2*j]   = e0;  b1[2*j]   = (__fp16)(v0_ - (float)e0);
    b0[2*j+1] = e1;  b1[2*j+1] = (__fp16)(v1_ - (float)e1);
    b2[2*j]   = e2;  b3[2*j]   = (__fp16)(v2_ - (float)e2);
    b2[2*j+1] = e3;  b3[2*j+1] = (__fp16)(v3_ - (float)e3);
  }
}

__global__ __launch_bounds__(256)
__attribute__((amdgpu_waves_per_eu(4, 5)))
void qc_main(const float* __restrict__ x, const __fp16* __restrict__ amat,
             float* __restrict__ out) {
  __shared__ float2 sst[DIM];        // 32768 B
  char* sb = (char*)sst;
  const int t = threadIdx.x;
  const long row = blockIdx.x;

  // ---- stage x row (im=0), accumulate sum of squares ----
  const float4* x4 = (const float4*)(x + (size_t)row * DIM);
  float ssq = 0.f;
#pragma unroll
  for (int k = 0; k < 4; ++k) {
    float4 a = x4[t + 256*k];
    int j0 = 4*(t + 256*k);
    *(float2*)(sb + (swz((unsigned)j0)     << 3)) = make_float2(a.x, 0.f);
    *(float2*)(sb + (swz((unsigned)(j0+1)) << 3)) = make_float2(a.y, 0.f);
    *(float2*)(sb + (swz((unsigned)(j0+2)) << 3)) = make_float2(a.z, 0.f);
    *(float2*)(sb + (swz((unsigned)(j0+3)) << 3)) = make_float2(a.w, 0.f);
    ssq += a.x*a.x + a.y*a.y + a.z*a.z + a.w*a.w;
  }
#pragma unroll
  for (int off = 32; off > 0; off >>= 1) ssq += __shfl_down(ssq, off, 64);
  __syncthreads();

  // ---- 9 rounds; each round = dense 16x16 complex gate-product via MFMA.
  // Wave w handles tiles 4w+tt (16 cosets each). Lane l: coset col = l&15,
  // slots 4q..4q+3 with q = l>>4 (A/B K-fragment AND C/D row mapping agree,
  // so per-lane read-set == write-set; no intra-round barrier needed).
#pragma unroll 1
  for (int r = 0; r < NROUND; ++r) {
    const unsigned s0 = PLAN.rd[r].s[0], sA = PLAN.rd[r].s[1];
    const unsigned sB = PLAN.rd[r].s[2], sC = PLAN.rd[r].s[3];
    const unsigned l0 = PLAN.rd[r].l[0], l1 = PLAN.rd[r].l[1];
    const unsigned l2 = PLAN.rd[r].l[2], l3 = PLAN.rd[r].l[3];
    const unsigned CB1 = PLAN.rd[r].cbsw8[1], CB2 = PLAN.rd[r].cbsw8[2];
    const unsigned CB3 = PLAN.rd[r].cbsw8[3];
    const unsigned C4 = PLAN.rd[r].cbsw8[4], C8 = PLAN.rd[r].cbsw8[8];
    const unsigned D1 = PLAN.rd[r].dt[1], D2 = PLAN.rd[r].dt[2];
    const unsigned D3 = PLAN.rd[r].dt[3];

    // coset for tile 0: c0 = wave*64 + (lane&15)
    unsigned j = ((unsigned)t & 0xC0u) | ((unsigned)t & 15u);
    j = ((j & ~l0) << 1) | (j & l0);
    j = ((j & ~l1) << 1) | (j & l1);
    j = ((j & ~l2) << 1) | (j & l2);
    j = ((j & ~l3) << 1) | (j & l3);
    unsigned adj8 = 0;
    adj8 ^= (unsigned)(-(int)(__popc(j & s0) & 1)) & CB1;
    adj8 ^= (unsigned)(-(int)(__popc(j & sA) & 1)) & CB2;
    adj8 ^= (unsigned)(-(int)(__popc(j & sB) & 1)) & C4;
    adj8 ^= (unsigned)(-(int)(__popc(j & sC) & 1)) & C8;
    const unsigned q = ((unsigned)t >> 4) & 3u;
    const unsigned qsel = ((q & 1u) ? C4 : 0u) ^ ((q & 2u) ? C8 : 0u);
    const unsigned b0a = (((j ^ (j >> 4)) << 3) ^ adj8) ^ qsel;

    // A-operand fragments (uniform-ish global loads; L1/L2 resident)
    const fp16x8* am = (const fp16x8*)(amat + (size_t)r * 2048);
    const int fo = (t & 15) * 4 + (int)q;
    const fp16x8 Arh = am[fo];
    const fp16x8 Arl = am[64 + fo];
    const fp16x8 Aih = am[128 + fo];
    const fp16x8 Ail = am[192 + fo];

#pragma unroll
    for (int tt = 0; tt < 4; ++tt) {
      const unsigned bb = b0a ^ (tt == 0 ? 0u : tt == 1 ? D1 : tt == 2 ? D2 : D3);
      const unsigned a0 = bb, a1 = bb ^ CB1, a2 = bb ^ CB2, a3 = bb ^ CB3;
      const float2 A0 = *(const float2*)(sb + a0);
      const float2 A1 = *(const float2*)(sb + a1);
      const float2 A2 = *(const float2*)(sb + a2);
      const float2 A3 = *(const float2*)(sb + a3);
      // B fragment: k = q*8 + 2*jj + comp -> amp slot 4q+jj, re/im interleave
      fp16x2 p0 = __builtin_amdgcn_cvt_pkrtz(A0.x, A0.y);
      fp16x2 p1 = __builtin_amdgcn_cvt_pkrtz(A1.x, A1.y);
      fp16x2 p2 = __builtin_amdgcn_cvt_pkrtz(A2.x, A2.y);
      fp16x2 p3 = __builtin_amdgcn_cvt_pkrtz(A3.x, A3.y);
      fp16x2 q0 = __builtin_amdgcn_cvt_pkrtz(A0.x - (float)p0[0], A0.y - (float)p0[1]);
      fp16x2 q1 = __builtin_amdgcn_cvt_pkrtz(A1.x - (float)p1[0], A1.y - (float)p1[1]);
      fp16x2 q2 = __builtin_amdgcn_cvt_pkrtz(A2.x - (float)p2[0], A2.y - (float)p2[1]);
      fp16x2 q3 = __builtin_amdgcn_cvt_pkrtz(A3.x - (float)p3[0], A3.y - (float)p3[1]);
      fp16x4 u01 = __builtin_shufflevector(p0, p1, 0, 1, 2, 3);
      fp16x4 u23 = __builtin_shufflevector(p2, p3, 0, 1, 2, 3);
      fp16x8 Bhi = __builtin_shufflevector(u01, u23, 0, 1, 2, 3, 4, 5, 6, 7);
      fp16x4 w01 = __builtin_shufflevector(q0, q1, 0, 1, 2, 3);
      fp16x4 w23 = __builtin_shufflevector(q2, q3, 0, 1, 2, 3);
      fp16x8 Blo = __builtin_shufflevector(w01, w23, 0, 1, 2, 3, 4, 5, 6, 7);

      // 6-term hi/lo product (lo x lo dropped: ~2^-24 rel, negligible)
      f32x4 are = {0.f, 0.f, 0.f, 0.f}, aim = {0.f, 0.f, 0.f, 0.f};
      are = __builtin_amdgcn_mfma_f32_16x16x32_f16(Arh, Bhi, are, 0, 0, 0);
      are = __builtin_amdgcn_mfma_f32_16x16x32_f16(Arl, Bhi, are, 0, 0, 0);
      are = __builtin_amdgcn_mfma_f32_16x16x32_f16(Arh, Blo, are, 0, 0, 0);
      aim = __builtin_amdgcn_mfma_f32_16x16x32_f16(Aih, Bhi, aim, 0, 0, 0);
      aim = __builtin_amdgcn_mfma_f32_16x16x32_f16(Ail, Bhi, aim, 0, 0, 0);
      aim = __builtin_amdgcn_mfma_f32_16x16x32_f16(Aih, Blo, aim, 0, 0, 0);

      // C/D layout: col = lane&15 (coset), row = q*4+reg (slot) -> same addrs
      *(float2*)(sb + a0) = make_float2(are[0], aim[0]);
      *(float2*)(sb + a1) = make_float2(are[1], aim[1]);
      *(float2*)(sb + a2) = make_float2(are[2], aim[2]);
      *(float2*)(sb + a3) = make_float2(are[3], aim[3]);
    }
    __syncthreads();
  }

  // ---- measurement: 16 consecutive amps/thread, WHT over low 4 bits ----
  const unsigned mbase8 = (((16u * (unsigned)t) ^ (unsigned)t) << 3);
  float p[16];
#pragma unroll
  for (int c = 0; c < 16; ++c) {
    float2 v = *(const float2*)(sb + (mbase8 ^ ((unsigned)c << 3)));
    p[c] = v.x * v.x + v.y * v.y;
  }
#pragma unroll
  for (int b = 0; b < 4; ++b) {
#pragma unroll
    for (int c = 0; c < 16; ++c) {
      if (!(c & (1 << b))) {
        const int c1 = c | (1 << b);
        float u = p[c], v = p[c1];
        p[c] = u + v; p[c1] = u - v;
      }
    }
  }
  float zs[NQ];
#pragma unroll
  for (int qq = 0; qq < NQ; ++qq) {
    const unsigned m = PLAN.zsel[qq];
    const float v = p[m & 15u];
    const int sgn = __popc((unsigned)t & (m >> 4)) & 1;
    zs[qq] = sgn ? -v : v;
  }

  // ---- block reduction via LDS (replaces 72-bpermute shfl tree) ----
  // layout: 6 float2 columns of 256 entries at k*2048; ssq at 12288;
  // partials at 12352.
  __syncthreads();               // all state reads done; safe to overwrite
#pragma unroll
  for (int k = 0; k < 6; ++k)
    *(float2*)(sb + (((unsigned)(k << 8) + (unsigned)t) << 3)) =
        make_float2(zs[2*k], zs[2*k+1]);
  if ((t & 63) == 0) *(float*)(sb + 12288 + (t >> 6) * 4) = ssq;
  __syncthreads();
  if (t < 192) {
    const int k = t >> 5, j = t & 31;
    const char* cbp = sb + (k << 11) + (j << 3);
    float2 acc = *(const float2*)(cbp);
#pragma unroll
    for (int i = 1; i < 8; ++i) {         // stride 32 entries: conflict-free
      float2 vv = *(const float2*)(cbp + i * 256);
      acc.x += vv.x; acc.y += vv.y;
    }
#pragma unroll
    for (int off = 16; off > 0; off >>= 1) {
      acc.x += __shfl_down(acc.x, off, 32);
      acc.y += __shfl_down(acc.y, off, 32);
    }
    if (j == 0) *(float2*)(sb + 12352 + (k << 3)) = acc;
  }
  __syncthreads();
  if (t < NQ) {
    const float* sq = (const float*)(sb + 12288);
    const float den = sq[0] + sq[1] + sq[2] + sq[3];
    out[row * NQ + t] = ((const float*)(sb + 12352))[t] / den;
  }
}

extern "C" void kernel_launch(void* const* d_in, const int* in_sizes, int n_in,
                              void* d_out, int out_size, void* d_ws, size_t ws_size,
                              hipStream_t stream) {
  const float* x = (const float*)d_in[0];
  const float* params = (const float*)d_in[1];
  float* out = (float*)d_out;
  __fp16* amat = (__fp16*)d_ws;                // 9 rounds * 4 mats * 16x32 fp16
  const int nrows = in_sizes[0] / DIM;         // 8192
  qc_prep<<<dim3(1), dim3(256), 0, stream>>>(params, amat);
  qc_main<<<dim3(nrows), dim3(256), 0, stream>>>(x, amat, out);
}